// Round 1
// baseline (99.094 us; speedup 1.0000x reference)
//
#include <hip/hip_runtime.h>
#include <hip/hip_bf16.h>

// ROC-AUC loss via Fourier CDF approximation.
// Phase 1 (k_partial): per-block masked sums of sin/cos(2*pi*k*s) for k=1..128
//   (pos-class and total; neg = total - pos), staged chunk in LDS, 1 harmonic
//   per thread, hardware v_sin/v_cos in revolutions (sin(2pi*k*s)=v_sin(fract(k*s))).
// Phase 2 (k_final): reduce partials, build integrated Fourier coeffs, evaluate
//   normalized CDFs at 1024 thresholds (1 per thread), Riemann AUC, write scalar.

#define NK 128
#define NSTEPS 1024
#define K1_TPB 256
#define CHUNK 512
#define PSTRIDE 520           // floats per block row: 512 sums + 1 count + pad
#define DET_BLOCKS 32
#define DET_TPB 256
#define K2_TPB 1024

__device__ __forceinline__ float wave_sum(float v) {
  #pragma unroll
  for (int off = 32; off > 0; off >>= 1) v += __shfl_down(v, off, 64);
  return v;
}

// Block-reduce to thread 0. scratch >= blockDim/64 floats. Callers must
// __syncthreads() before reusing scratch.
__device__ __forceinline__ float block_sum(float v, float* scratch) {
  int lane = threadIdx.x & 63, wid = threadIdx.x >> 6;
  v = wave_sum(v);
  if (lane == 0) scratch[wid] = v;
  __syncthreads();
  float r = 0.0f;
  if (threadIdx.x == 0) {
    int nw = blockDim.x >> 6;
    for (int w = 0; w < nw; ++w) r += scratch[w];
  }
  return r;
}

// ---- dtype detection for `targets` (bool could arrive as u8 / i32 / f32) ----
// Scans only the first N BYTES (safe under every interpretation) and records a
// byte-lane OR. i32 {0,1} -> 0x00000001 ; u8 {0,1} -> 0x01010101 ;
// f32 {0.0,1.0} -> 0x3F800000.
__global__ __launch_bounds__(DET_TPB) void k_detect(const unsigned char* __restrict__ t,
                                                    int nbytes,
                                                    unsigned* __restrict__ flags) {
  __shared__ unsigned s_or;
  if (threadIdx.x == 0) s_or = 0u;
  __syncthreads();
  unsigned local = 0u;
  int n16 = nbytes >> 4;
  const uint4* p = (const uint4*)t;
  for (int i = blockIdx.x * DET_TPB + threadIdx.x; i < n16; i += DET_BLOCKS * DET_TPB) {
    uint4 v = p[i];
    local |= v.x | v.y | v.z | v.w;
  }
  if (blockIdx.x == 0 && threadIdx.x < (nbytes & 15)) {
    int i = (n16 << 4) + threadIdx.x;
    local |= ((unsigned)t[i]) << ((i & 3) * 8);
  }
  if (local) atomicOr(&s_or, local);
  __syncthreads();
  if (threadIdx.x == 0) flags[blockIdx.x] = s_or;
}

__device__ __forceinline__ int decode_mode(const unsigned* __restrict__ flags) {
  unsigned o = 0u;
  #pragma unroll
  for (int i = 0; i < DET_BLOCKS; ++i) o |= flags[i];
  bool nz0 = (o & 0xFFu) != 0u;
  bool nz1 = (o & 0xFF00u) != 0u;
  bool nz23 = (o & 0xFFFF0000u) != 0u;
  if (!nz1 && !nz23) return 1;  // int32 values {0,1}
  if (!nz0 && !nz1) return 2;   // float32 values {0.0,1.0}
  return 0;                     // uint8 / bool
}

// ---- phase 1: partial masked Fourier sums ----
__global__ __launch_bounds__(K1_TPB) void k_partial(const float* __restrict__ scores,
                                                    const unsigned char* __restrict__ tgt,
                                                    int N,
                                                    const unsigned* __restrict__ flags,
                                                    float* __restrict__ partials) {
  __shared__ float2 s_d[CHUNK];       // (score, mask)
  __shared__ float s_comb[NK * 4];    // half==1 partials for combine
  __shared__ float s_red[K1_TPB / 64];
  const int mode = decode_mode(flags);
  const int base = blockIdx.x * CHUNK;

  float lc = 0.0f;  // positive count (each sample loaded exactly once)
  for (int i = threadIdx.x; i < CHUNK; i += K1_TPB) {
    int g = base + i;
    float s = 0.0f, m = 0.0f;
    if (g < N) {
      s = scores[g];
      if (mode == 0)      m = (float)tgt[g];
      else if (mode == 1) m = (float)((const int*)tgt)[g];
      else                m = ((const float*)tgt)[g];
    }
    s_d[i] = make_float2(s, m);
    lc += m;
  }
  __syncthreads();
  float cnt = block_sum(lc, s_red);  // valid on thread 0 only

  const int k_idx = threadIdx.x & (NK - 1);
  const int half = threadIdx.x >> 7;  // 0 or 1
  const float kf = (float)(k_idx + 1);
  const int HC = CHUNK / 2;
  const int i0 = half * HC;

  float ps = 0.0f, pc = 0.0f, ts = 0.0f, tc = 0.0f;
  #pragma unroll 4
  for (int i = 0; i < HC; ++i) {
    float2 d = s_d[i0 + i];  // LDS broadcast (same addr across wave) - no conflicts
    float x = kf * d.x;
    float f = __builtin_amdgcn_fractf(x);         // k*s mod 1 (revolutions)
    float sn = __builtin_amdgcn_sinf(f);          // sin(2*pi*k*s)
    float cs = __builtin_amdgcn_cosf(f);          // cos(2*pi*k*s)
    ts += sn;
    tc += cs;
    ps = fmaf(d.y, sn, ps);
    pc = fmaf(d.y, cs, pc);
  }
  // padded (g>=N) entries have s=0,m=0 -> contributed cos(0)=1 to tc only; remove
  int valid = min(max(N - base - i0, 0), HC);
  tc -= (float)(HC - valid);

  if (half == 1) {
    s_comb[k_idx * 4 + 0] = ps;
    s_comb[k_idx * 4 + 1] = pc;
    s_comb[k_idx * 4 + 2] = ts;
    s_comb[k_idx * 4 + 3] = tc;
  }
  __syncthreads();
  float* ob = partials + (size_t)blockIdx.x * PSTRIDE;
  if (half == 0) {
    float4 o;
    o.x = ps + s_comb[k_idx * 4 + 0];
    o.y = pc + s_comb[k_idx * 4 + 1];
    o.z = ts + s_comb[k_idx * 4 + 2];
    o.w = tc + s_comb[k_idx * 4 + 3];
    ((float4*)ob)[k_idx] = o;  // contiguous 512 floats per block, coalesced
  }
  if (threadIdx.x == 0) ob[NK * 4] = cnt;
}

// ---- phase 2: reduce, coefficients, CDF eval, AUC ----
__global__ __launch_bounds__(K2_TPB) void k_final(const float* __restrict__ partials,
                                                  int nblocks, int N,
                                                  float* __restrict__ out) {
  __shared__ float s_tmp[K2_TPB];
  __shared__ float s_sums[NK * 4];
  __shared__ float s_isp[NK], s_icp[NK], s_isn[NK], s_icn[NK];
  __shared__ float s_pn[NSTEPS + 2], s_nn[NSTEPS + 2];
  __shared__ float s_red[K2_TPB / 64];
  __shared__ float s_npos;
  const int tid = threadIdx.x;

  // Phase A: reduce 512 quantities over blocks; 2 threads per quantity
  {
    int q = tid & 511;
    int hb = tid >> 9;  // 0/1: which half of the block range
    int bph = (nblocks + 1) >> 1;
    int b0 = hb * bph;
    int b1 = min(nblocks, b0 + bph);
    float acc = 0.0f;
    #pragma unroll 8
    for (int b = b0; b < b1; ++b) acc += partials[(size_t)b * PSTRIDE + q];
    s_tmp[tid] = acc;
  }
  float cl = 0.0f;
  for (int b = tid; b < nblocks; b += K2_TPB) cl += partials[(size_t)b * PSTRIDE + NK * 4];
  __syncthreads();
  if (tid < NK * 4) s_sums[tid] = s_tmp[tid] + s_tmp[tid + 512];
  float np = block_sum(cl, s_red);
  if (tid == 0) s_npos = np;
  __syncthreads();

  // Phase B: integrated Fourier coefficients for both classes
  if (tid < NK) {
    const float eps = 1.1920929e-07f;  // FLT_EPSILON, matches jnp.finfo(f32).eps
    float npos = s_npos;
    float nneg = (float)N - npos;
    float sp = s_sums[tid * 4 + 0], cp = s_sums[tid * 4 + 1];
    float st = s_sums[tid * 4 + 2], ct = s_sums[tid * 4 + 3];
    float scp, ccp, scn, ccn;
    if (npos < eps) { scp = 0.0f; ccp = 0.0f; }
    else { float d = fmaxf(npos, eps); scp = sp / d; ccp = cp / d; }
    if (nneg < eps) { scn = 0.0f; ccn = 0.0f; }
    else { float d = fmaxf(nneg, eps); scn = (st - sp) / d; ccn = (ct - cp) / d; }
    float w = 6.2831853071795864769f * (float)(tid + 1);  // fl(2*pi)*k, as reference
    s_isp[tid] = ccp / w;  s_icp[tid] = -scp / w;
    s_isn[tid] = ccn / w;  s_icn[tid] = -scn / w;
  }
  __syncthreads();

  // Phase C: normalized CDFs at 1024 thresholds, one per thread
  {
    float thr = (float)tid * (1.0f / 1023.0f);
    float cp_acc = 0.0f, cn_acc = 0.0f;
    #pragma unroll 4
    for (int k = 0; k < NK; ++k) {
      float x = (float)(k + 1) * thr;
      float f = __builtin_amdgcn_fractf(x);
      float sn = __builtin_amdgcn_sinf(f);
      float cs = __builtin_amdgcn_cosf(f);
      cp_acc += sn * s_isp[k] + cs * s_icp[k];
      cn_acc += sn * s_isn[k] + cs * s_icn[k];
    }
    s_pn[tid + 1] = 1.0f - 0.5f * (cp_acc + 0.5f);
    s_nn[tid + 1] = 1.0f - 0.5f * (cn_acc + 0.5f);
  }
  if (tid == 0) {
    s_pn[0] = 1.0f; s_nn[0] = 1.0f;
    s_pn[NSTEPS + 1] = 0.0f; s_nn[NSTEPS + 1] = 0.0f;
  }
  __syncthreads();

  // Phase D: Riemann AUC both directions
  float pa = 0.0f, na = 0.0f;
  for (int i = tid; i < NSTEPS + 1; i += K2_TPB) {
    float p0 = s_pn[i], p1 = s_pn[i + 1];
    float n0 = s_nn[i], n1 = s_nn[i + 1];
    pa = fmaf(p0, n0 - n1, pa);   // pos_norm[i] * (-diff(neg_norm))[i]
    na = fmaf(n0, p1 - p0, na);   // neg_norm[i] * diff(pos_norm)[i]
  }
  float paS = block_sum(pa, s_red);
  __syncthreads();
  float naS = block_sum(na, s_red);
  if (tid == 0) out[0] = 0.5f * (paS + (1.0f + naS));
}

extern "C" void kernel_launch(void* const* d_in, const int* in_sizes, int n_in,
                              void* d_out, int out_size, void* d_ws, size_t ws_size,
                              hipStream_t stream) {
  const float* scores = (const float*)d_in[0];
  const unsigned char* targets = (const unsigned char*)d_in[1];
  const int N = in_sizes[0];

  unsigned* flags = (unsigned*)d_ws;
  float* partials = (float*)((char*)d_ws + 1024);

  const int nblocks = (N + CHUNK - 1) / CHUNK;  // 512 for N=262144

  k_detect<<<DET_BLOCKS, DET_TPB, 0, stream>>>(targets, N, flags);
  k_partial<<<nblocks, K1_TPB, 0, stream>>>(scores, targets, N, flags, partials);
  k_final<<<1, K2_TPB, 0, stream>>>(partials, nblocks, N, (float*)d_out);
}